// Round 6
// baseline (630.652 us; speedup 1.0000x reference)
//
#include <hip/hip_runtime.h>
#include <math.h>

#define N_NODES 100000
#define N_EDGES 1600000
#define TWO_E   (2 * N_EDGES)
#define DIM 64
#define SCAN_BLOCKS 98  // ceil(100000/1024)

// ex = exp(sigmoid(as+ad)) — same formula everywhere so denom contributions
// bit-match the per-edge numerators.
__device__ __forceinline__ float edge_ex(float as, float ad) {
    float x = as + ad;
    float sg = 1.0f / (1.0f + __expf(-x));
    return __expf(sg);
}

// K1: per-node attention projections. One wave per node, lane d owns dim d.
__global__ __launch_bounds__(256) void att_kernel(const float* __restrict__ q,
                                                  const float* __restrict__ W_att,
                                                  float* __restrict__ att_src,
                                                  float* __restrict__ att_dst) {
    int wave = (blockIdx.x * blockDim.x + threadIdx.x) >> 6;
    int lane = threadIdx.x & 63;
    if (wave >= N_NODES) return;
    float qv = q[wave * DIM + lane];
    float ps = qv * W_att[lane];
    float pd = qv * W_att[DIM + lane];
    #pragma unroll
    for (int off = 32; off >= 1; off >>= 1) {
        ps += __shfl_xor(ps, off);
        pd += __shfl_xor(pd, off);
    }
    if (lane == 0) {
        att_src[wave] = ps;
        att_dst[wave] = pd;
    }
}

// K2: histogram by dst — FIRE-AND-FORGET atomics (no returned rank, so waves
// never stall on the atomic result; ranks are assigned later in scatter).
__global__ __launch_bounds__(256) void hist_kernel(const int* __restrict__ dst1,
                                                   const int* __restrict__ dst2,
                                                   int* __restrict__ count) {
    int idx = blockIdx.x * blockDim.x + threadIdx.x;
    if (idx >= TWO_E) return;
    int d = (idx < N_EDGES) ? dst1[idx] : dst2[idx - N_EDGES];
    atomicAdd(count + d, 1);   // return value unused -> no sc0, no wait
}

// K3a: per-block exclusive scan of count -> offsets (block-local), block sums.
__global__ __launch_bounds__(1024) void scan1_kernel(const int* __restrict__ count,
                                                     int* __restrict__ offsets,
                                                     int* __restrict__ bsum) {
    __shared__ int wtot[16];
    int i = blockIdx.x * 1024 + threadIdx.x;
    int v = (i < N_NODES) ? count[i] : 0;
    int lane = threadIdx.x & 63, wid = threadIdx.x >> 6;
    int x = v;
    #pragma unroll
    for (int off = 1; off <= 32; off <<= 1) {
        int y = __shfl_up(x, off);
        if (lane >= off) x += y;
    }
    if (lane == 63) wtot[wid] = x;
    __syncthreads();
    if (threadIdx.x < 16) {
        int t = wtot[threadIdx.x];
        #pragma unroll
        for (int off = 1; off <= 8; off <<= 1) {
            int y = __shfl_up(t, off);
            if (threadIdx.x >= off) t += y;
        }
        wtot[threadIdx.x] = t;  // inclusive scan of wave totals
    }
    __syncthreads();
    int woff = (wid == 0) ? 0 : wtot[wid - 1];
    if (i < N_NODES) offsets[i] = woff + x - v;  // exclusive within block
    if (threadIdx.x == 0) bsum[blockIdx.x] = wtot[15];
}

// K3b: scan the 98 block sums (tiny, single block).
__global__ __launch_bounds__(128) void scan2_kernel(const int* __restrict__ bsum,
                                                    int* __restrict__ boff) {
    __shared__ int s[SCAN_BLOCKS];
    if (threadIdx.x < SCAN_BLOCKS) s[threadIdx.x] = bsum[threadIdx.x];
    __syncthreads();
    if (threadIdx.x == 0) {
        int run = 0;
        for (int b = 0; b < SCAN_BLOCKS; ++b) { int t = s[b]; s[b] = run; run += t; }
    }
    __syncthreads();
    if (threadIdx.x < SCAN_BLOCKS) boff[threadIdx.x] = s[threadIdx.x];
}

// K3c: add block offsets; also materialize the scatter cursor copy.
__global__ __launch_bounds__(1024) void scan3_kernel(int* __restrict__ offsets,
                                                     const int* __restrict__ boff,
                                                     int* __restrict__ cursor) {
    int i = blockIdx.x * 1024 + threadIdx.x;
    if (i < N_NODES) {
        int v = offsets[i] + boff[blockIdx.x];
        offsets[i] = v;
        cursor[i] = v;
    }
    if (i == N_NODES - 1) offsets[N_NODES] = TWO_E;
}

// K4: scatter edge records into CSR buckets. Slot comes from a returning
// atomicAdd on cursor — the latency overlaps this thread's other work
// (edge loads, edge_ex math, record store). Record: {src | type<<31, ex}.
__global__ __launch_bounds__(256) void scatter_kernel(const int* __restrict__ src1, const int* __restrict__ dst1,
                                                      const int* __restrict__ src2, const int* __restrict__ dst2,
                                                      const float* __restrict__ att_src, const float* __restrict__ att_dst,
                                                      int* __restrict__ cursor,
                                                      uint2* __restrict__ recs) {
    int idx = blockIdx.x * blockDim.x + threadIdx.x;
    if (idx >= TWO_E) return;
    int s, d; unsigned tb;
    if (idx < N_EDGES) { s = src1[idx]; d = dst1[idx]; tb = 0u; }
    else               { s = src2[idx - N_EDGES]; d = dst2[idx - N_EDGES]; tb = 0x80000000u; }
    int pos = atomicAdd(cursor + d, 1);          // issue early; result needed late
    float ex = edge_ex(att_src[s], att_dst[d]);
    recs[pos] = make_uint2((unsigned)s | tb, __float_as_uint(ex));
}

// K5: gather-reduce per node. 16 threads/node, each owns a float4 chunk.
// Sweep 1: per-type denominators (in-register, shfl reduce).
// Sweep 2: S[n] += (ex/denom) * q[src], one plain float4 store at the end.
__global__ __launch_bounds__(256) void gather_kernel(const float* __restrict__ q,
                                                     const int* __restrict__ offsets,
                                                     const uint2* __restrict__ recs,
                                                     float* __restrict__ S,
                                                     float* __restrict__ fbuf) {
    int node = blockIdx.x * 16 + (threadIdx.x >> 4);
    int t = threadIdx.x & 15;
    if (node >= N_NODES) return;
    int beg = offsets[node], end = offsets[node + 1];
    float d1 = 0.f, d2 = 0.f;
    for (int i = beg + t; i < end; i += 16) {
        uint2 r = recs[i];
        float ex = __uint_as_float(r.y);
        if ((int)r.x < 0) d2 += ex; else d1 += ex;
    }
    #pragma unroll
    for (int off = 8; off >= 1; off >>= 1) {
        d1 += __shfl_xor(d1, off);
        d2 += __shfl_xor(d2, off);
    }
    float inv1 = (d1 > 0.f) ? (1.0f / d1) : 0.f;
    float inv2 = (d2 > 0.f) ? (1.0f / d2) : 0.f;
    if (t == 0) fbuf[node] = ((d1 > 0.f) ? 1.f : 0.f) + ((d2 > 0.f) ? 1.f : 0.f);

    float4 acc = make_float4(0.f, 0.f, 0.f, 0.f);
    const float* qb = q + t * 4;
    int i = beg;
    for (; i + 1 < end; i += 2) {  // unroll x2 for memory-level parallelism
        uint2 r0 = recs[i], r1 = recs[i + 1];
        int s0 = r0.x & 0x7fffffff, s1 = r1.x & 0x7fffffff;
        float a0 = __uint_as_float(r0.y) * (((int)r0.x < 0) ? inv2 : inv1);
        float a1 = __uint_as_float(r1.y) * (((int)r1.x < 0) ? inv2 : inv1);
        const float4 q0 = *reinterpret_cast<const float4*>(qb + (size_t)s0 * DIM);
        const float4 q1 = *reinterpret_cast<const float4*>(qb + (size_t)s1 * DIM);
        acc.x += a0 * q0.x; acc.y += a0 * q0.y; acc.z += a0 * q0.z; acc.w += a0 * q0.w;
        acc.x += a1 * q1.x; acc.y += a1 * q1.y; acc.z += a1 * q1.z; acc.w += a1 * q1.w;
    }
    if (i < end) {
        uint2 r = recs[i];
        int s = r.x & 0x7fffffff;
        float a = __uint_as_float(r.y) * (((int)r.x < 0) ? inv2 : inv1);
        const float4 qv = *reinterpret_cast<const float4*>(qb + (size_t)s * DIM);
        acc.x += a * qv.x; acc.y += a * qv.y; acc.z += a * qv.z; acc.w += a * qv.w;
    }
    *reinterpret_cast<float4*>(S + (size_t)node * DIM + t * 4) = acc;
}

// K6: per-node epilogue, wave-task version. Block = 512 threads = 8 waves
// covering 64 nodes (lane = node). Each wave owns one (m, c) task:
//   m=0: OV chunk c  = S_row @ W_V[c*16..].T + f*b_V   (overwrites S in place)
//   m=1: q_new chunk c = (2q+S)_row @ W_upd[c*16..].T
// m,c go through readfirstlane -> SGPR, so every weight address is provably
// wave-uniform -> s_load + v_fmac(sgpr, vgpr). __syncthreads separates all
// S-reads from the in-place OV overwrite.
__global__ __launch_bounds__(512) void final_kernel(const float* __restrict__ q,
                                                    const float* __restrict__ W_upd,
                                                    const float* __restrict__ W_V,
                                                    const float* __restrict__ b_V,
                                                    const float* __restrict__ fbuf,
                                                    float* __restrict__ q_new,
                                                    float* S_and_OV) {
    int lane = threadIdx.x & 63;
    int w = threadIdx.x >> 6;                               // 0..7
    int ms = __builtin_amdgcn_readfirstlane(w >> 2);        // 0: OV, 1: q_new
    int cs = __builtin_amdgcn_readfirstlane(w & 3);         // output chunk
    int node = blockIdx.x * 64 + lane;
    bool active = node < N_NODES;

    float r[DIM];
    float f = 0.f;
    if (active) {
        const float* srow = S_and_OV + (size_t)node * DIM;
        if (ms == 0) {
            #pragma unroll
            for (int k = 0; k < 16; ++k) {
                float4 v = *reinterpret_cast<const float4*>(srow + 4 * k);
                r[4 * k + 0] = v.x; r[4 * k + 1] = v.y;
                r[4 * k + 2] = v.z; r[4 * k + 3] = v.w;
            }
            f = fbuf[node];
        } else {
            const float* qrow = q + (size_t)node * DIM;
            #pragma unroll
            for (int k = 0; k < 16; ++k) {
                float4 sv = *reinterpret_cast<const float4*>(srow + 4 * k);
                float4 qv = *reinterpret_cast<const float4*>(qrow + 4 * k);
                r[4 * k + 0] = 2.f * qv.x + sv.x;
                r[4 * k + 1] = 2.f * qv.y + sv.y;
                r[4 * k + 2] = 2.f * qv.z + sv.z;
                r[4 * k + 3] = 2.f * qv.w + sv.w;
            }
        }
    } else {
        #pragma unroll
        for (int d = 0; d < DIM; ++d) r[d] = 0.f;
    }

    __syncthreads();  // all S reads done before OV overwrites S

    const float* Wbase = ms ? W_upd : W_V;
    float acc[16];
    #pragma unroll
    for (int j = 0; j < 16; ++j) acc[j] = (ms == 0) ? f * b_V[cs * 16 + j] : 0.f;
    #pragma unroll
    for (int j = 0; j < 16; ++j) {
        const float* wr = Wbase + (cs * 16 + j) * DIM;  // wave-uniform -> s_load
        float a = acc[j];
        #pragma unroll
        for (int d = 0; d < DIM; ++d) a += r[d] * wr[d];
        acc[j] = a;
    }

    if (active) {
        float* outp = (ms ? q_new : S_and_OV) + (size_t)node * DIM + cs * 16;
        #pragma unroll
        for (int k = 0; k < 4; ++k)
            *reinterpret_cast<float4*>(outp + 4 * k) =
                make_float4(acc[4 * k], acc[4 * k + 1], acc[4 * k + 2], acc[4 * k + 3]);
    }
}

extern "C" void kernel_launch(void* const* d_in, const int* in_sizes, int n_in,
                              void* d_out, int out_size, void* d_ws, size_t ws_size,
                              hipStream_t stream) {
    const float* q     = (const float*)d_in[0];
    const float* W_att = (const float*)d_in[1];
    const float* W_upd = (const float*)d_in[2];
    const float* W_V   = (const float*)d_in[3];
    const float* b_V   = (const float*)d_in[4];
    const int*   src1  = (const int*)d_in[5];
    const int*   dst1  = (const int*)d_in[6];
    const int*   src2  = (const int*)d_in[7];
    const int*   dst2  = (const int*)d_in[8];

    float* out   = (float*)d_out;
    float* q_new = out;                              // [N,64] final; holds recs until then
    float* S     = out + (size_t)N_NODES * DIM;      // [N,64]: S, then OV in-place
    uint2* recs  = (uint2*)q_new;                    // 2E * 8B == N*DIM*4B exactly

    float* att_src = (float*)d_ws;                   // N
    float* att_dst = att_src + N_NODES;              // N
    float* fbuf    = att_dst + N_NODES;              // N
    int*   count   = (int*)(fbuf + N_NODES);         // N
    int*   offsets = count + N_NODES;                // N+1
    int*   cursor  = offsets + N_NODES + 1;          // N
    int*   bsum    = cursor + N_NODES;               // 128
    int*   boff    = bsum + 128;                     // 128

    hipMemsetAsync(count, 0, (size_t)N_NODES * sizeof(int), stream);

    att_kernel<<<N_NODES / 4, 256, 0, stream>>>(q, W_att, att_src, att_dst);
    hist_kernel<<<(TWO_E + 255) / 256, 256, 0, stream>>>(dst1, dst2, count);
    scan1_kernel<<<SCAN_BLOCKS, 1024, 0, stream>>>(count, offsets, bsum);
    scan2_kernel<<<1, 128, 0, stream>>>(bsum, boff);
    scan3_kernel<<<SCAN_BLOCKS, 1024, 0, stream>>>(offsets, boff, cursor);
    scatter_kernel<<<(TWO_E + 255) / 256, 256, 0, stream>>>(
        src1, dst1, src2, dst2, att_src, att_dst, cursor, recs);
    gather_kernel<<<(N_NODES + 15) / 16, 256, 0, stream>>>(q, offsets, recs, S, fbuf);
    final_kernel<<<(N_NODES + 63) / 64, 512, 0, stream>>>(
        q, W_upd, W_V, b_V, fbuf, q_new, S);
}

// Round 8
// 463.661 us; speedup vs baseline: 1.3602x; 1.3602x over previous
//
#include <hip/hip_runtime.h>
#include <math.h>

#define N_NODES 100000
#define N_EDGES 1600000
#define TWO_E   (2 * N_EDGES)
#define DIM 64
#define NB 1563          // ceil(100000 / 64) coarse buckets of 64 nodes
#define EPB 16384        // edges per block in hist/scatter
#define HS_BLOCKS ((TWO_E + EPB - 1) / EPB)   // 196
#define CAP 2048         // records per LDS sort chunk in gather

// ex = exp(sigmoid(as+ad)) — same formula everywhere so denom contributions
// bit-match the per-edge numerators.
__device__ __forceinline__ float edge_ex(float as, float ad) {
    float x = as + ad;
    float sg = 1.0f / (1.0f + __expf(-x));
    return __expf(sg);
}

// K1: per-node attention projections. One wave per node, lane d owns dim d.
__global__ __launch_bounds__(256) void att_kernel(const float* __restrict__ q,
                                                  const float* __restrict__ W_att,
                                                  float* __restrict__ att_src,
                                                  float* __restrict__ att_dst) {
    int wave = (blockIdx.x * blockDim.x + threadIdx.x) >> 6;
    int lane = threadIdx.x & 63;
    if (wave >= N_NODES) return;
    float qv = q[wave * DIM + lane];
    float ps = qv * W_att[lane];
    float pd = qv * W_att[DIM + lane];
    #pragma unroll
    for (int off = 32; off >= 1; off >>= 1) {
        ps += __shfl_xor(ps, off);
        pd += __shfl_xor(pd, off);
    }
    if (lane == 0) {
        att_src[wave] = ps;
        att_dst[wave] = pd;
    }
}

// K2: coarse histogram (bucket = dst>>6) with per-block LDS aggregation.
// Global atomics: one fire-and-forget add per (block, bucket) = ~306k total.
__global__ __launch_bounds__(1024) void hist_coarse(const int* __restrict__ dst1,
                                                    const int* __restrict__ dst2,
                                                    int* __restrict__ bcount) {
    __shared__ int lh[NB];
    for (int b = threadIdx.x; b < NB; b += 1024) lh[b] = 0;
    __syncthreads();
    int base = blockIdx.x * EPB;
    int lim = min(base + EPB, TWO_E);
    for (int idx = base + threadIdx.x; idx < lim; idx += 1024) {
        int d = (idx < N_EDGES) ? dst1[idx] : dst2[idx - N_EDGES];
        atomicAdd(&lh[d >> 6], 1);
    }
    __syncthreads();
    for (int b = threadIdx.x; b < NB; b += 1024)
        if (lh[b]) atomicAdd(bcount + b, lh[b]);
}

// K3: exclusive scan of 1563 bucket counts -> base (+ sentinel) and cursor copy.
__global__ __launch_bounds__(1024) void scan_coarse(const int* __restrict__ bcount,
                                                    int* __restrict__ bbase,
                                                    int* __restrict__ bcursor) {
    __shared__ int wt[16];
    int t = threadIdx.x;
    int i0 = 2 * t, i1 = 2 * t + 1;
    int v0 = (i0 < NB) ? bcount[i0] : 0;
    int v1 = (i1 < NB) ? bcount[i1] : 0;
    int p = v0 + v1;
    int lane = t & 63, wid = t >> 6;
    int x = p;
    #pragma unroll
    for (int off = 1; off <= 32; off <<= 1) {
        int y = __shfl_up(x, off);
        if (lane >= off) x += y;
    }
    if (lane == 63) wt[wid] = x;
    __syncthreads();
    if (t < 16) {
        int s = wt[t];
        #pragma unroll
        for (int off = 1; off <= 8; off <<= 1) {
            int y = __shfl_up(s, off);
            if (t >= off) s += y;
        }
        wt[t] = s;
    }
    __syncthreads();
    int pre = ((wid ? wt[wid - 1] : 0)) + (x - p);   // exclusive base of pair
    if (i0 < NB) { bbase[i0] = pre;      bcursor[i0] = pre; }
    if (i1 < NB) { bbase[i1] = pre + v0; bcursor[i1] = pre + v0; }
    if (t == 0) bbase[NB] = wt[15];
}

// K4: coarse scatter. Per-block LDS histogram -> ONE returning global
// atomicAdd per (block,bucket) reserves a contiguous run; in-block rank via
// LDS atomics. Record: word0 = src(17b) | type<<17 | (dst&63)<<18, word1 = ex.
__global__ __launch_bounds__(1024) void scatter_coarse(const int* __restrict__ src1, const int* __restrict__ dst1,
                                                       const int* __restrict__ src2, const int* __restrict__ dst2,
                                                       const float* __restrict__ att_src, const float* __restrict__ att_dst,
                                                       int* __restrict__ bcursor,
                                                       uint2* __restrict__ recs) {
    __shared__ int lh[NB];
    __shared__ int gb[NB];
    __shared__ int lc[NB];
    for (int b = threadIdx.x; b < NB; b += 1024) lh[b] = 0;
    __syncthreads();
    int base = blockIdx.x * EPB;
    int lim = min(base + EPB, TWO_E);
    for (int idx = base + threadIdx.x; idx < lim; idx += 1024) {
        int d = (idx < N_EDGES) ? dst1[idx] : dst2[idx - N_EDGES];
        atomicAdd(&lh[d >> 6], 1);
    }
    __syncthreads();
    for (int b = threadIdx.x; b < NB; b += 1024) {
        int c = lh[b];
        lc[b] = 0;
        gb[b] = c ? atomicAdd(bcursor + b, c) : 0;   // aggregated reservation
    }
    __syncthreads();
    for (int idx = base + threadIdx.x; idx < lim; idx += 1024) {
        int s, d; unsigned ty;
        if (idx < N_EDGES) { s = src1[idx]; d = dst1[idx]; ty = 0u; }
        else               { s = src2[idx - N_EDGES]; d = dst2[idx - N_EDGES]; ty = 1u; }
        int b = d >> 6;
        int r = atomicAdd(&lc[b], 1);                // cheap LDS rank
        float ex = edge_ex(att_src[s], att_dst[d]);
        recs[gb[b] + r] = make_uint2((unsigned)s | (ty << 17) | ((unsigned)(d & 63) << 18),
                                     __float_as_uint(ex));
    }
}

// K5: gather. One block per bucket (64 nodes, 1024 threads = 64 groups x 16).
// Per CAP chunk: LDS counting-sort records by node; then each 16-thread group
// iterates ALL of its node's records (LDS broadcast), every thread applying
// each record to its OWN dim chunk (redundant across threads — this is what
// round 7 got wrong). Per-type sums stay UNNORMALIZED in registers
// (acc_t = sum ex*q, d_t = sum ex); normalize once at the end:
// S = acc1/d1 + acc2/d2. No denominator pre-pass, zero global atomics.
__global__ __launch_bounds__(1024) void gather_coarse(const float* __restrict__ q,
                                                      const int* __restrict__ bbase,
                                                      const uint2* __restrict__ recs,
                                                      float* __restrict__ S,
                                                      float* __restrict__ fbuf) {
    __shared__ uint2 srt[CAP];
    __shared__ int cnt[64];
    __shared__ int cb[64];
    int tid = threadIdx.x;
    int bkt = blockIdx.x;
    int beg = bbase[bkt], end = bbase[bkt + 1];
    int g = tid >> 4, t16 = tid & 15;

    float4 acc1 = make_float4(0.f, 0.f, 0.f, 0.f);
    float4 acc2 = make_float4(0.f, 0.f, 0.f, 0.f);
    float d1 = 0.f, d2 = 0.f;    // identical across the 16 threads of a group

    for (int cbeg = beg; cbeg < end; cbeg += CAP) {
        int C = min(CAP, end - cbeg);
        __syncthreads();                       // prev chunk consumed
        if (tid < 64) cnt[tid] = 0;
        __syncthreads();
        uint2 r0, r1; int n0 = -1, n1 = -1, rk0 = 0, rk1 = 0;
        if (tid < C) {
            r0 = recs[cbeg + tid];
            n0 = (r0.x >> 18) & 63;
            rk0 = atomicAdd(&cnt[n0], 1);
        }
        if (tid + 1024 < C) {
            r1 = recs[cbeg + tid + 1024];
            n1 = (r1.x >> 18) & 63;
            rk1 = atomicAdd(&cnt[n1], 1);
        }
        __syncthreads();
        if (tid < 64) {                        // wave 0: exclusive scan of cnt
            int c = cnt[tid];
            int incl = c;
            #pragma unroll
            for (int off = 1; off <= 32; off <<= 1) {
                int y = __shfl_up(incl, off);
                if (tid >= off) incl += y;
            }
            cb[tid] = incl - c;
        }
        __syncthreads();
        if (n0 >= 0) srt[cb[n0] + rk0] = r0;
        if (n1 >= 0) srt[cb[n1] + rk1] = r1;
        __syncthreads();
        int s0 = cb[g], e0 = s0 + cnt[g];
        for (int k = s0; k < e0; ++k) {        // ALL 16 threads see ALL records
            uint2 r = srt[k];                  // LDS broadcast within group
            int s = r.x & 0x1FFFF;
            float exv = __uint_as_float(r.y);
            int ty = (r.x >> 17) & 1;
            float w1 = ty ? 0.f : exv;
            float w2 = ty ? exv : 0.f;
            d1 += w1; d2 += w2;
            const float4 qv = *reinterpret_cast<const float4*>(q + (size_t)s * DIM + t16 * 4);
            acc1.x += w1 * qv.x; acc1.y += w1 * qv.y; acc1.z += w1 * qv.z; acc1.w += w1 * qv.w;
            acc2.x += w2 * qv.x; acc2.y += w2 * qv.y; acc2.z += w2 * qv.z; acc2.w += w2 * qv.w;
        }
    }

    float inv1 = (d1 > 0.f) ? 1.0f / d1 : 0.f;
    float inv2 = (d2 > 0.f) ? 1.0f / d2 : 0.f;
    int node = bkt * 64 + g;
    if (node < N_NODES) {
        float4 sv;
        sv.x = acc1.x * inv1 + acc2.x * inv2;
        sv.y = acc1.y * inv1 + acc2.y * inv2;
        sv.z = acc1.z * inv1 + acc2.z * inv2;
        sv.w = acc1.w * inv1 + acc2.w * inv2;
        *reinterpret_cast<float4*>(S + (size_t)node * DIM + t16 * 4) = sv;
        if (t16 == 0)
            fbuf[node] = ((d1 > 0.f) ? 1.f : 0.f) + ((d2 > 0.f) ? 1.f : 0.f);
    }
}

// K6: per-node epilogue, wave-task version (unchanged from round 5).
__global__ __launch_bounds__(512) void final_kernel(const float* __restrict__ q,
                                                    const float* __restrict__ W_upd,
                                                    const float* __restrict__ W_V,
                                                    const float* __restrict__ b_V,
                                                    const float* __restrict__ fbuf,
                                                    float* __restrict__ q_new,
                                                    float* S_and_OV) {
    int lane = threadIdx.x & 63;
    int w = threadIdx.x >> 6;                               // 0..7
    int ms = __builtin_amdgcn_readfirstlane(w >> 2);        // 0: OV, 1: q_new
    int cs = __builtin_amdgcn_readfirstlane(w & 3);         // output chunk
    int node = blockIdx.x * 64 + lane;
    bool active = node < N_NODES;

    float r[DIM];
    float f = 0.f;
    if (active) {
        const float* srow = S_and_OV + (size_t)node * DIM;
        if (ms == 0) {
            #pragma unroll
            for (int k = 0; k < 16; ++k) {
                float4 v = *reinterpret_cast<const float4*>(srow + 4 * k);
                r[4 * k + 0] = v.x; r[4 * k + 1] = v.y;
                r[4 * k + 2] = v.z; r[4 * k + 3] = v.w;
            }
            f = fbuf[node];
        } else {
            const float* qrow = q + (size_t)node * DIM;
            #pragma unroll
            for (int k = 0; k < 16; ++k) {
                float4 sv = *reinterpret_cast<const float4*>(srow + 4 * k);
                float4 qv = *reinterpret_cast<const float4*>(qrow + 4 * k);
                r[4 * k + 0] = 2.f * qv.x + sv.x;
                r[4 * k + 1] = 2.f * qv.y + sv.y;
                r[4 * k + 2] = 2.f * qv.z + sv.z;
                r[4 * k + 3] = 2.f * qv.w + sv.w;
            }
        }
    } else {
        #pragma unroll
        for (int d = 0; d < DIM; ++d) r[d] = 0.f;
    }

    __syncthreads();  // all S reads done before OV overwrites S

    const float* Wbase = ms ? W_upd : W_V;
    float acc[16];
    #pragma unroll
    for (int j = 0; j < 16; ++j) acc[j] = (ms == 0) ? f * b_V[cs * 16 + j] : 0.f;
    #pragma unroll
    for (int j = 0; j < 16; ++j) {
        const float* wr = Wbase + (cs * 16 + j) * DIM;  // wave-uniform -> s_load
        float a = acc[j];
        #pragma unroll
        for (int d = 0; d < DIM; ++d) a += r[d] * wr[d];
        acc[j] = a;
    }

    if (active) {
        float* outp = (ms ? q_new : S_and_OV) + (size_t)node * DIM + cs * 16;
        #pragma unroll
        for (int k = 0; k < 4; ++k)
            *reinterpret_cast<float4*>(outp + 4 * k) =
                make_float4(acc[4 * k], acc[4 * k + 1], acc[4 * k + 2], acc[4 * k + 3]);
    }
}

extern "C" void kernel_launch(void* const* d_in, const int* in_sizes, int n_in,
                              void* d_out, int out_size, void* d_ws, size_t ws_size,
                              hipStream_t stream) {
    const float* q     = (const float*)d_in[0];
    const float* W_att = (const float*)d_in[1];
    const float* W_upd = (const float*)d_in[2];
    const float* W_V   = (const float*)d_in[3];
    const float* b_V   = (const float*)d_in[4];
    const int*   src1  = (const int*)d_in[5];
    const int*   dst1  = (const int*)d_in[6];
    const int*   src2  = (const int*)d_in[7];
    const int*   dst2  = (const int*)d_in[8];

    float* out   = (float*)d_out;
    float* q_new = out;                              // [N,64] final; holds recs until then
    float* S     = out + (size_t)N_NODES * DIM;      // [N,64]: S, then OV in-place
    uint2* recs  = (uint2*)q_new;                    // 2E * 8B == N*DIM*4B exactly

    float* att_src = (float*)d_ws;                   // N
    float* att_dst = att_src + N_NODES;              // N
    float* fbuf    = att_dst + N_NODES;              // N
    int*   bcount  = (int*)(fbuf + N_NODES);         // NB
    int*   bbase   = bcount + NB;                    // NB+1
    int*   bcursor = bbase + NB + 1;                 // NB

    hipMemsetAsync(bcount, 0, NB * sizeof(int), stream);

    att_kernel<<<N_NODES / 4, 256, 0, stream>>>(q, W_att, att_src, att_dst);
    hist_coarse<<<HS_BLOCKS, 1024, 0, stream>>>(dst1, dst2, bcount);
    scan_coarse<<<1, 1024, 0, stream>>>(bcount, bbase, bcursor);
    scatter_coarse<<<HS_BLOCKS, 1024, 0, stream>>>(
        src1, dst1, src2, dst2, att_src, att_dst, bcursor, recs);
    gather_coarse<<<NB, 1024, 0, stream>>>(q, bbase, recs, S, fbuf);
    final_kernel<<<(N_NODES + 63) / 64, 512, 0, stream>>>(
        q, W_upd, W_V, b_V, fbuf, q_new, S);
}